// Round 15
// baseline (644.745 us; speedup 1.0000x reference)
//
#include <hip/hip_runtime.h>
#include <hip/hip_bf16.h>

typedef unsigned short u16;
typedef unsigned int u32;
typedef __attribute__((ext_vector_type(8))) short s16x8;
typedef __attribute__((ext_vector_type(4))) float f32x4;

#define MFMA_BF16(a, b, c) __builtin_amdgcn_mfma_f32_16x16x32_bf16(a, b, c, 0, 0, 0)

__device__ __forceinline__ u16 f2bf(float f) {
  union { float f; u32 u; } c; c.f = f;
  return (u16)((c.u + 0x7FFFu + ((c.u >> 16) & 1u)) >> 16);
}

__device__ __forceinline__ u32 pkbf(float a, float b) {
  float2 t; t.x = a; t.y = b;
  __hip_bfloat162 h = __float22bfloat162_rn(t);
  union { __hip_bfloat162 h; u32 u; } c; c.h = h; return c.u;
}

__device__ __forceinline__ void gll16(const void* g, void* l) {
  __builtin_amdgcn_global_load_lds((const __attribute__((address_space(1))) void*)g,
                                   (__attribute__((address_space(3))) void*)l, 16, 0, 0);
}

__device__ __forceinline__ f32x4 f4zero() { f32x4 z = {0.f, 0.f, 0.f, 0.f}; return z; }

// ---------------- prep: f32 -> bf16 convert ----------------
__global__ void cvt_bf16_kernel(const float4* __restrict__ in, u16* __restrict__ out, int n4) {
  int i = blockIdx.x * 256 + threadIdx.x;
  if (i >= n4) return;
  float4 v = in[i];
  uint2 w;
  w.x = (u32)f2bf(v.x) | ((u32)f2bf(v.y) << 16);
  w.y = (u32)f2bf(v.z) | ((u32)f2bf(v.w) << 16);
  *reinterpret_cast<uint2*>(out + (size_t)i * 4) = w;
}

// ---------------- prep: transpose + convert to FRAGMENT-LINEAR bf16 ----------------
// (proven correct in R13.) out fragment (nb, kt): element (n,k) at
// out[((nb*KT)+kt)*512 + (q*16+li)*8 + e], q=(k>>3)&3, e=k&7, li=n&15, KT=R/32.
// A wave's MFMA B-frag load = out[fragbase + lane*8 .. +7]: fully coalesced 1 KB.
__global__ void transpose_cvt_frag_kernel(const float* __restrict__ in, u16* __restrict__ out,
                                          int R, int C) {
  __shared__ float tile[32][33];
  int tx = threadIdx.x, ty = threadIdx.y;
  int r0 = blockIdx.y * 32, c0 = blockIdx.x * 32;   // r: K dim, c: N dim
#pragma unroll
  for (int i = 0; i < 32; i += 8)
    tile[ty + i][tx] = in[(size_t)(r0 + ty + i) * C + c0 + tx];
  __syncthreads();
  const int KT = R >> 5;
  const int kt = r0 >> 5;
  const int q = tx >> 3, e = tx & 7;
#pragma unroll
  for (int i = 0; i < 32; i += 8) {
    const int n = c0 + ty + i;
    const int nb = n >> 4, li2 = n & 15;
    out[((size_t)nb * KT + kt) * 512 + (q * 16 + li2) * 8 + e] = f2bf(tile[tx][ty + i]);
  }
}

// =====================================================================================
// 128x256 GEMM, BK=32. A via LDS (3-parity, 24 KB, paired-row XOR conflict-free,
// R12-proven). B DIRECT from fragment-linear global with ONE-TILE REGISTER PREFETCH
// (the R13 regression was no-prefetch: L2 latency exposed per tile; two named B sets
// alternate, so MFMA's compiler vmcnt wait on B(t) -- issued a full tile ago -- is
// free). LDS pipe now carries only A (32 KB rd + 8 KB wr per block-tile); B rides
// the parallel L2 pipe (panel L2-resident via the R14 locality walk).
// vmcnt ledger (in-order queue): steady tile end outstanding =
//   {A(t+1), B(t+1)x4, A(t+2)} = 6 -> VM5 drains A(t+1) exactly.
//   prologue: B(0)x4, A(0), A(1) -> VM1. tile126: VM4 (drains A(127)). tile127: none.
// L2-locality walk (R14): bn = raw>>5, bm = ((raw>>3)&3)*8 + (raw&7).
// EPI 1: q/k/v scatter epilogue (KV cols 4096..4351 are the bn=16 block).
// =====================================================================================

#define BARRIER __builtin_amdgcn_s_barrier()
#define SCHEDB __builtin_amdgcn_sched_barrier(0)
#define PRIO1 __builtin_amdgcn_s_setprio(1)
#define PRIO0 __builtin_amdgcn_s_setprio(0)
#define VM5 asm volatile("s_waitcnt vmcnt(5)" ::: "memory")
#define VM4 asm volatile("s_waitcnt vmcnt(4)" ::: "memory")
#define VM1 asm volatile("s_waitcnt vmcnt(1)" ::: "memory")

#define PAB(P) ((P) * 8192)

#define RDA(P) do { _Pragma("unroll")                                                    \
  for (int mi2 = 0; mi2 < 4; ++mi2)                                                      \
    a[mi2] = *(const s16x8*)(smem + PAB(P) + aOff + mi2*1024);                           \
} while (0)

#define LDB(BSET, T) do { _Pragma("unroll")                                              \
  for (int ni2 = 0; ni2 < 4; ++ni2)                                                      \
    BSET[ni2] = *(const s16x8*)(Bw + ((size_t)ni2 * 128 + (T)) * 512);                   \
} while (0)

#define MFMA16(BSET) do { _Pragma("unroll")                                              \
  for (int mi2 = 0; mi2 < 4; ++mi2) { _Pragma("unroll")                                  \
    for (int ni2 = 0; ni2 < 4; ++ni2)                                                    \
      acc[mi2][ni2] = MFMA_BF16(a[mi2], BSET[ni2], acc[mi2][ni2]);                       \
  } } while (0)

#define STAGE1(P, kn) gll16(srcA + (kn), smem + PAB(P) + tt*16)

// BU = B set consumed this tile; BL = B set loaded for tile T+1
#define TILE(PR, PS, T, BU, BL) do {                                                     \
  s16x8 a[4];                                                                            \
  LDB(BL, (T) + 1);                                                                      \
  STAGE1(PS, ((T) + 2) * 32);                                                            \
  RDA(PR);                                                                               \
  SCHEDB;                                                                                \
  PRIO1; MFMA16(BU); PRIO0;                                                              \
  SCHEDB;                                                                                \
  VM5;                                                                                   \
  BARRIER;                                                                               \
} while (0)

template<int EPI>
__global__ __launch_bounds__(512, 4)
void gemm128_kernel(const u16* __restrict__ A, const u16* __restrict__ Bf,
                    float* __restrict__ Cf, u16* __restrict__ Cq,
                    u16* __restrict__ Ck, u16* __restrict__ Cvt,
                    int N) {
  __shared__ __align__(16) char smem[24576];
  const int tt = threadIdx.x;
  const int w = tt >> 6, l = tt & 63;
  const int li = l & 15, g = l >> 4;
  const int wm = w >> 2, wn = w & 3;

  // L2-locality walk (bijective): 32 consecutive raw ids share one bn (B panel)
  const int gx = gridDim.x;
  const int raw = blockIdx.y * gx + blockIdx.x;
  const int bn = raw >> 5;
  const int bm = ((raw >> 3) & 3) * 8 + (raw & 7);

  f32x4 acc[4][4];
#pragma unroll
  for (int i = 0; i < 4; ++i)
#pragma unroll
    for (int j = 0; j < 4; ++j) acc[i][j] = f4zero();

  // ---- A staging source (inverse paired-row + slot-XOR map on the source) ----
  const int sg = (tt & 7) ^ ((tt >> 3) & 7);
  const int ar = 2 * (tt >> 3) + (sg >> 2);
  const int aq = sg & 3;
  const u16* srcA = A + (size_t)(bm * 128 + ar) * 4096 + aq * 8;

  // ---- B fragment base for this wave (fragment-linear, KT = 128) ----
  const u16* Bw = Bf + ((size_t)(bn * 16 + wn * 4) * 128) * 512 + l * 8;

  // ---- A ds_read per-thread byte offsets (slot XOR, 128B lines; conflict-free) ----
  const int slot = (((li & 1) * 4 + g) ^ ((li >> 1) & 7)) * 16;
  const int aOff = wm * 4096 + (li >> 1) * 128 + slot;   // + mi*1024 per fragment

  // B register double-buffer (named sets, static indexing only)
  s16x8 bA[4], bB[4];

  // ---- prologue: B(0) into bA; stage A tiles 0,1; drain A(0) ----
  LDB(bA, 0);
  STAGE1(0, 0);
  STAGE1(1, 32);
  VM1;
  BARRIER;

  // ---- main loop: 128 K-tiles, period 6 (3 A-parities x 2 B-sets) ----
  for (int t6 = 0; t6 < 126; t6 += 6) {
    TILE(0, 2, t6 + 0, bA, bB);
    TILE(1, 0, t6 + 1, bB, bA);
    TILE(2, 1, t6 + 2, bA, bB);
    TILE(0, 2, t6 + 3, bB, bA);
    TILE(1, 0, t6 + 4, bA, bB);
    TILE(2, 1, t6 + 5, bB, bA);
  }
  // tile 126 (parity 0, uses bA, loads bB=B(127), no stage): drain A(127)
  {
    s16x8 a[4];
    LDB(bB, 127);
    RDA(0);
    SCHEDB;
    PRIO1; MFMA16(bA); PRIO0;
    SCHEDB;
    VM4;
    BARRIER;
  }
  // tile 127 (parity 1, uses bB)
  {
    s16x8 a[4];
    RDA(1);
    SCHEDB;
    PRIO1; MFMA16(bB); PRIO0;
  }

  // ---- epilogue ----
#pragma unroll
  for (int mi = 0; mi < 4; ++mi) {
#pragma unroll
    for (int ni = 0; ni < 4; ++ni) {
      const int row0 = bm * 128 + wm * 64 + mi * 16 + g * 4;
      const int col = bn * 256 + wn * 64 + ni * 16 + li;
#pragma unroll
      for (int r = 0; r < 4; ++r) {
        const int m = row0 + r;
        const float v = acc[mi][ni][r];
        if (EPI == 0) {
          Cf[(size_t)m * N + col] = v;
        } else {
          const int bb2 = m >> 11, s = m & 2047;
          const int kt = s >> 5;
          const size_t tb = (size_t)(bb2 * 64 + kt);
          if (col < 4096) {
            Cq[(size_t)m * 4096 + col] = f2bf(v);
          } else if (col < 4224) {
            const int d = col - 4096, kr = s & 31;
            const int mk = kr >> 4, lii = kr & 15;
            const int kk = d >> 5, gg = (d >> 3) & 3, e = d & 7;
            Ck[(tb * 8 + mk * 4 + kk) * 512 + (gg * 16 + lii) * 8 + e] = f2bf(v);
          } else {
            const int d = col - 4224, kp = s & 31;
            const int mf = d >> 4, lii = d & 15;
            const int gg = kp >> 3, e = kp & 7;
            Cvt[(tb * 8 + mf) * 512 + (gg * 16 + lii) * 8 + e] = f2bf(v);
          }
        }
      }
    }
  }
}

// ---------------- flash attention (MQA) ----------------
// 1 wave/block; block p handles q-tiles {63-p, p} (uniform 66 tile-units).
// K double-buffered in registers; V issued at tile top; fragment-linear K/V loads.

__device__ __forceinline__ void load_ktile(s16x8 (&dst)[8], const u16* kf, size_t tb, int l) {
#pragma unroll
  for (int f = 0; f < 8; ++f)
    dst[f] = *(const s16x8*)&kf[(tb * 8 + f) * 512 + l * 8];
}

template<bool DIAG>
__device__ __forceinline__ void attn_tile(
    int kt, const u16* kf, const u16* vf, size_t bb64, int l, int li, int g,
    s16x8 (&use)[8], s16x8 (&fill)[8], bool do_fill,
    const s16x8 (&bq)[2][4], f32x4 (&acc)[8][2],
    float (&m_)[2], float (&lp)[2], float (&bias)[2],
    float c1, const float (&cjr)[8], float bstep, u16 (*Pw)[40]) {
  const size_t tb = bb64 + kt;
  s16x8 vr[8];
#pragma unroll
  for (int f = 0; f < 8; ++f)
    vr[f] = *(const s16x8*)&vf[(tb * 8 + f) * 512 + l * 8];
  if (do_fill) load_ktile(fill, kf, tb - 1, l);

  f32x4 sc[2][2];
  sc[0][0] = f4zero(); sc[0][1] = f4zero(); sc[1][0] = f4zero(); sc[1][1] = f4zero();
#pragma unroll
  for (int kk = 0; kk < 4; ++kk)
#pragma unroll
    for (int mk = 0; mk < 2; ++mk) {
      sc[mk][0] = MFMA_BF16(use[mk * 4 + kk], bq[0][kk], sc[mk][0]);
      sc[mk][1] = MFMA_BF16(use[mk * 4 + kk], bq[1][kk], sc[mk][1]);
    }

#pragma unroll
  for (int nq = 0; nq < 2; ++nq) {
    float sv[8];
    float pm = -3e38f;
    if (DIAG) {
#pragma unroll
      for (int mk = 0; mk < 2; ++mk)
#pragma unroll
        for (int r = 0; r < 4; ++r) {
          const int kd = mk * 16 + g * 4 + r - (nq * 16 + li);
          float s = fmaf(sc[mk][nq][r], c1, bias[nq] + cjr[mk * 4 + r]);
          s = (kd <= 0) ? s : -1e30f;
          sv[mk * 4 + r] = s;
          pm = fmaxf(pm, s);
        }
      pm = fmaxf(pm, __shfl_xor(pm, 16));
      pm = fmaxf(pm, __shfl_xor(pm, 32));
      m_[nq] = pm;
    } else {
#pragma unroll
      for (int mk = 0; mk < 2; ++mk)
#pragma unroll
        for (int r = 0; r < 4; ++r) {
          float s = fmaf(sc[mk][nq][r], c1, bias[nq] + cjr[mk * 4 + r]);
          sv[mk * 4 + r] = s;
          pm = fmaxf(pm, s);
        }
      if (__any(pm > m_[nq])) {
        pm = fmaxf(pm, __shfl_xor(pm, 16));
        pm = fmaxf(pm, __shfl_xor(pm, 32));
        const float nm = fmaxf(m_[nq], pm);
        const float scale = exp2f(m_[nq] - nm);
#pragma unroll
        for (int mf = 0; mf < 8; ++mf) acc[mf][nq] *= scale;
        lp[nq] *= scale;
        m_[nq] = nm;
      }
    }
    const float mref = m_[nq];
    float e[8];
#pragma unroll
    for (int j = 0; j < 8; ++j) e[j] = exp2f(sv[j] - mref);
    lp[nq] += ((e[0] + e[1]) + (e[2] + e[3])) + ((e[4] + e[5]) + (e[6] + e[7]));
#pragma unroll
    for (int mk = 0; mk < 2; ++mk) {
      uint2 wv;
      wv.x = pkbf(e[mk * 4 + 0], e[mk * 4 + 1]);
      wv.y = pkbf(e[mk * 4 + 2], e[mk * 4 + 3]);
      *reinterpret_cast<uint2*>(&Pw[nq * 16 + li][mk * 16 + g * 4]) = wv;
    }
    bias[nq] -= bstep;
  }

  s16x8 pb0 = *(const s16x8*)&Pw[li][g * 8];
  s16x8 pb1 = *(const s16x8*)&Pw[16 + li][g * 8];
#pragma unroll
  for (int mf = 0; mf < 8; ++mf) {
    acc[mf][0] = MFMA_BF16(vr[mf], pb0, acc[mf][0]);
    acc[mf][1] = MFMA_BF16(vr[mf], pb1, acc[mf][1]);
  }
}

__device__ __forceinline__ void attn_qtile(
    int qt, int h, int b, const u16* qbuf, const u16* kf, const u16* vf,
    u16* obuf, int l, int li, int g, float c1, float sl2, u16 (*Pw)[40]) {
  const int S = 2048;
  const int q0 = qt * 32;
  const size_t bb64 = (size_t)b * 64;

  s16x8 bq[2][4];
#pragma unroll
  for (int nq = 0; nq < 2; ++nq)
#pragma unroll
    for (int kk = 0; kk < 4; ++kk)
      bq[nq][kk] = *(const s16x8*)&qbuf[(size_t)(b * S + q0 + nq * 16 + li) * 4096
                                        + h * 128 + kk * 32 + g * 8];

  f32x4 acc[8][2];
#pragma unroll
  for (int mf = 0; mf < 8; ++mf) { acc[mf][0] = f4zero(); acc[mf][1] = f4zero(); }
  float m_[2] = {-3e38f, -3e38f};
  float lp[2] = {0.f, 0.f};

  float cjr[8];
#pragma unroll
  for (int j = 0; j < 8; ++j) cjr[j] = sl2 * (float)((j >> 2) * 16 + (j & 3));
  float bias[2];
#pragma unroll
  for (int nq = 0; nq < 2; ++nq)
    bias[nq] = sl2 * (float)(g * 4 - nq * 16 - li);
  const float bstep = sl2 * 32.f;

  s16x8 kA[8], kB[8];
  load_ktile(kA, kf, bb64 + qt, l);
  attn_tile<true>(qt, kf, vf, bb64, l, li, g, kA, kB, qt >= 1,
                  bq, acc, m_, lp, bias, c1, cjr, bstep, Pw);
  int kt = qt - 1;
  while (kt >= 1) {
    attn_tile<false>(kt, kf, vf, bb64, l, li, g, kB, kA, true,
                     bq, acc, m_, lp, bias, c1, cjr, bstep, Pw);
    attn_tile<false>(kt - 1, kf, vf, bb64, l, li, g, kA, kB, kt >= 2,
                     bq, acc, m_, lp, bias, c1, cjr, bstep, Pw);
    kt -= 2;
  }
  if (kt == 0)
    attn_tile<false>(0, kf, vf, bb64, l, li, g, kB, kA, false,
                     bq, acc, m_, lp, bias, c1, cjr, bstep, Pw);

#pragma unroll
  for (int nq = 0; nq < 2; ++nq) {
    float ls = lp[nq];
    ls += __shfl_xor(ls, 16);
    ls += __shfl_xor(ls, 32);
    const float inv = 1.f / ls;
    const size_t rowbase = (size_t)(b * S + q0 + nq * 16 + li) * 4096 + h * 128;
#pragma unroll
    for (int mf = 0; mf < 8; ++mf) {
      f32x4 v = acc[mf][nq];
      uint2 wv;
      wv.x = pkbf(v[0] * inv, v[1] * inv);
      wv.y = pkbf(v[2] * inv, v[3] * inv);
      *reinterpret_cast<uint2*>(&obuf[rowbase + mf * 16 + g * 4]) = wv;
    }
  }
}

__global__ __launch_bounds__(64, 2)
void attn_kernel(const u16* __restrict__ qbuf, const u16* __restrict__ kf,
                 const u16* __restrict__ vf, u16* __restrict__ obuf) {
  const int p = blockIdx.x, h = blockIdx.y, b = blockIdx.z;
  const int l = threadIdx.x, li = l & 15, g = l >> 4;
  const float L2E = 1.4426950408889634f;
  const float slope = exp2f(-0.25f * (float)(h + 1));
  const float c1 = 0.08838834764831845f * L2E;
  const float sl2 = slope * L2E;
  __shared__ __align__(16) u16 P[32][40];
  attn_qtile(63 - p, h, b, qbuf, kf, vf, obuf, l, li, g, c1, sl2, P);
  attn_qtile(p, h, b, qbuf, kf, vf, obuf, l, li, g, c1, sl2, P);
}

// ---------------- launch ----------------
extern "C" void kernel_launch(void* const* d_in, const int* in_sizes, int n_in,
                              void* d_out, int out_size, void* d_ws, size_t ws_size,
                              hipStream_t stream) {
  (void)in_sizes; (void)n_in; (void)out_size; (void)ws_size;
  const float* hidden = (const float*)d_in[0];
  const float* w_qkv = (const float*)d_in[1];
  const float* w_c = (const float*)d_in[2];
  float* out = (float*)d_out;
  char* ws = (char*)d_ws;

  // workspace layout (100 MB total)
  u16* hid_bf = (u16*)(ws + 0);            // 32 MB  (B*S,4096) bf16; reused as attn out
  u16* wT     = (u16*)(ws + 33554432);     // 34 MB  w_qkv / w_c fragment-linear bf16
  u16* qbuf   = (u16*)(ws + 69206016);     // 32 MB  (B*S,4096) bf16
  u16* kbuf   = (u16*)(ws + 102760448);    // 1 MB   K fragment-linear
  u16* vtbuf  = (u16*)(ws + 103809024);    // 1 MB   V fragment-linear

  cvt_bf16_kernel<<<16384, 256, 0, stream>>>((const float4*)hidden, hid_bf, 4194304);
  transpose_cvt_frag_kernel<<<dim3(136, 128), dim3(32, 8), 0, stream>>>(w_qkv, wT, 4096, 4352);
  gemm128_kernel<1><<<dim3(17, 32), 512, 0, stream>>>(hid_bf, wT, nullptr, qbuf, kbuf, vtbuf,
                                                      4352);
  attn_kernel<<<dim3(32, 32, 2), 64, 0, stream>>>(qbuf, kbuf, vtbuf, hid_bf);
  transpose_cvt_frag_kernel<<<dim3(128, 128), dim3(32, 8), 0, stream>>>(w_c, wT, 4096, 4096);
  gemm128_kernel<0><<<dim3(16, 32), 512, 0, stream>>>(hid_bf, wT, out, nullptr, nullptr, nullptr,
                                                      4096);
}

// Round 16
// 481.072 us; speedup vs baseline: 1.3402x; 1.3402x over previous
//
#include <hip/hip_runtime.h>
#include <hip/hip_bf16.h>

typedef unsigned short u16;
typedef unsigned int u32;
typedef __attribute__((ext_vector_type(8))) short s16x8;
typedef __attribute__((ext_vector_type(4))) float f32x4;

#define MFMA_BF16(a, b, c) __builtin_amdgcn_mfma_f32_16x16x32_bf16(a, b, c, 0, 0, 0)

__device__ __forceinline__ u16 f2bf(float f) {
  union { float f; u32 u; } c; c.f = f;
  return (u16)((c.u + 0x7FFFu + ((c.u >> 16) & 1u)) >> 16);
}

__device__ __forceinline__ u32 pkbf(float a, float b) {
  float2 t; t.x = a; t.y = b;
  __hip_bfloat162 h = __float22bfloat162_rn(t);
  union { __hip_bfloat162 h; u32 u; } c; c.h = h; return c.u;
}

__device__ __forceinline__ void gll16(const void* g, void* l) {
  __builtin_amdgcn_global_load_lds((const __attribute__((address_space(1))) void*)g,
                                   (__attribute__((address_space(3))) void*)l, 16, 0, 0);
}

__device__ __forceinline__ f32x4 f4zero() { f32x4 z = {0.f, 0.f, 0.f, 0.f}; return z; }

// ---------------- prep: f32 -> bf16 convert ----------------
__global__ void cvt_bf16_kernel(const float4* __restrict__ in, u16* __restrict__ out, int n4) {
  int i = blockIdx.x * 256 + threadIdx.x;
  if (i >= n4) return;
  float4 v = in[i];
  uint2 w;
  w.x = (u32)f2bf(v.x) | ((u32)f2bf(v.y) << 16);
  w.y = (u32)f2bf(v.z) | ((u32)f2bf(v.w) << 16);
  *reinterpret_cast<uint2*>(out + (size_t)i * 4) = w;
}

// ---------------- prep: transpose + convert (R x C f32 -> C x R bf16) ----------------
__global__ void transpose_cvt_kernel(const float* __restrict__ in, u16* __restrict__ out,
                                     int R, int C) {
  __shared__ float tile[32][33];
  int tx = threadIdx.x, ty = threadIdx.y;
  int r0 = blockIdx.y * 32, c0 = blockIdx.x * 32;
#pragma unroll
  for (int i = 0; i < 32; i += 8)
    tile[ty + i][tx] = in[(size_t)(r0 + ty + i) * C + c0 + tx];
  __syncthreads();
#pragma unroll
  for (int i = 0; i < 32; i += 8)
    out[(size_t)(c0 + ty + i) * R + r0 + tx] = f2bf(tile[tx][ty + i]);
}

// =====================================================================================
// 128x256 GEMM, BK=32, TRIPLE-buffered 72 KB LDS (2 blocks/CU) with counted vmcnt
// (R12 structure + R14 locality walk = best measured: 182 us, conflicts 0).
// L2-LOCALITY WALK: bn = raw>>5 (32 consecutive raws share ONE 2MB B panel -> fits
// XCD L2; L3 serves cross-XCD reuse); bm = ((raw>>3)&3)*8 + (raw&7). Bijective.
// LDS layout (conflict-free): paired rows, (row r, granule q) at line (r>>1),
// slot ((r&1)*4+q) ^ ((r>>1)&7); read slot = ((li&1)*4+g) ^ ((li>>1)&7).
// gll16 writes linear tt*16; inverse map on SOURCE: sg=(tt&7)^((tt>>3)&7),
// row = 2*(tt>>3)+(sg>>2), granule = sg&3.
// Ledger: tile t reads parity t%3, stages t+2 into (t+2)%3, waits vmcnt(3) at tile
// end (drains stage(t+1); stage(t+2) stays in flight). Barrier/tile for WAR.
// NOTE (R15 lesson): at __launch_bounds__(512,4) the unified VGPR+AGPR budget is 128
// per wave; persistent operand double-buffers (+32 regs) spill -> do not re-add.
// EPI 1: q/k/v scatter epilogue (KV cols 4096..4351 are the bn=16 block).
// =====================================================================================

#define BARRIER __builtin_amdgcn_s_barrier()
#define SCHEDB __builtin_amdgcn_sched_barrier(0)
#define PRIO1 __builtin_amdgcn_s_setprio(1)
#define PRIO0 __builtin_amdgcn_s_setprio(0)
#define VM3 asm volatile("s_waitcnt vmcnt(3)" ::: "memory")
#define VM0 asm volatile("s_waitcnt vmcnt(0)" ::: "memory")
#define NOPW do {} while (0)

#define PAB(P) ((P) * 8192)
#define PBB(P) (24576 + (P) * 16384)

#define RDAB(P) do { _Pragma("unroll")                                                   \
  for (int mi2 = 0; mi2 < 4; ++mi2)                                                      \
    a[mi2] = *(const s16x8*)(smem + PAB(P) + aOff + mi2*1024);                           \
  _Pragma("unroll")                                                                      \
  for (int ni2 = 0; ni2 < 4; ++ni2)                                                      \
    b[ni2] = *(const s16x8*)(smem + PBB(P) + bOff + ni2*1024);                           \
} while (0)

#define MFMA16 do { _Pragma("unroll")                                                    \
  for (int mi2 = 0; mi2 < 4; ++mi2) { _Pragma("unroll")                                  \
    for (int ni2 = 0; ni2 < 4; ++ni2)                                                    \
      acc[mi2][ni2] = MFMA_BF16(a[mi2], b[ni2], acc[mi2][ni2]);                          \
  } } while (0)

#define STAGE3(P, kn) do {                                                               \
  gll16(srcA + (kn), smem + PAB(P) + tt*16);                                             \
  gll16(srcB0 + (kn), smem + PBB(P) + tt*16);                                            \
  gll16(srcB1 + (kn), smem + PBB(P) + 8192 + tt*16);                                     \
} while (0)

#define TILE_S(PR, PS, T) do {                                                           \
  s16x8 a[4], b[4];                                                                      \
  RDAB(PR);                                                                              \
  STAGE3(PS, ((T) + 2) * 32);                                                            \
  SCHEDB;                                                                                \
  PRIO1; MFMA16; PRIO0;                                                                  \
  SCHEDB;                                                                                \
  VM3;                                                                                   \
  BARRIER;                                                                               \
} while (0)

#define TILE_T(PR, WAIT) do {                                                            \
  s16x8 a[4], b[4];                                                                      \
  RDAB(PR);                                                                              \
  SCHEDB;                                                                                \
  PRIO1; MFMA16; PRIO0;                                                                  \
  SCHEDB;                                                                                \
  WAIT;                                                                                  \
  BARRIER;                                                                               \
} while (0)

template<int EPI>
__global__ __launch_bounds__(512, 4)
void gemm128_kernel(const u16* __restrict__ A, const u16* __restrict__ Bt,
                    float* __restrict__ Cf, u16* __restrict__ Cq,
                    u16* __restrict__ Ck, u16* __restrict__ Cvt,
                    int N, int K) {
  __shared__ __align__(16) char smem[73728];
  const int tt = threadIdx.x;
  const int w = tt >> 6, l = tt & 63;
  const int li = l & 15, g = l >> 4;
  const int wm = w >> 2, wn = w & 3;

  // L2-locality walk (bijective): 32 consecutive raw ids share one bn (B panel);
  // per-XCD (raw&7 fixed) bm set is {x, x+8, x+16, x+24} for A locality.
  const int gx = gridDim.x;
  const int raw = blockIdx.y * gx + blockIdx.x;
  const int bn = raw >> 5;
  const int bm = ((raw >> 3) & 3) * 8 + (raw & 7);

  f32x4 acc[4][4];
#pragma unroll
  for (int i = 0; i < 4; ++i)
#pragma unroll
    for (int j = 0; j < 4; ++j) acc[i][j] = f4zero();

  // ---- staging sources (inverse paired-row + slot-XOR map on the source) ----
  const int sg = (tt & 7) ^ ((tt >> 3) & 7);
  const int ar = 2 * (tt >> 3) + (sg >> 2);
  const int aq = sg & 3;
  const u16* srcA = A + (size_t)(bm * 128 + ar) * K + aq * 8;
  const u16* srcB0 = Bt + (size_t)(bn * 256 + ar) * K + aq * 8;
  const u16* srcB1 = srcB0 + (size_t)128 * K;

  // ---- ds_read per-thread byte offsets (slot XOR by (li>>1)&7, 128B lines) ----
  const int slot = (((li & 1) * 4 + g) ^ ((li >> 1) & 7)) * 16;
  const int aOff = wm * 4096 + (li >> 1) * 128 + slot;   // + mi*1024 per fragment
  const int bOff = wn * 4096 + (li >> 1) * 128 + slot;   // + ni*1024 per fragment

  // ---- prologue: stage tiles 0,1 into parities 0,1; drain stage0 only ----
  STAGE3(0, 0);
  STAGE3(1, 32);
  VM3;
  BARRIER;

  // ---- main loop: 128 K-tiles (K == 4096, BK == 32), 3 per iteration ----
  for (int t3 = 0; t3 < 126; t3 += 3) {
    TILE_S(0, 2, t3);
    TILE_S(1, 0, t3 + 1);
    TILE_S(2, 1, t3 + 2);
  }
  TILE_T(0, VM0);    // tile 126: drain stage(127)
  TILE_T(1, NOPW);   // tile 127

  // ---- epilogue ----
#pragma unroll
  for (int mi = 0; mi < 4; ++mi) {
#pragma unroll
    for (int ni = 0; ni < 4; ++ni) {
      const int row0 = bm * 128 + wm * 64 + mi * 16 + g * 4;
      const int col = bn * 256 + wn * 64 + ni * 16 + li;
#pragma unroll
      for (int r = 0; r < 4; ++r) {
        const int m = row0 + r;
        const float v = acc[mi][ni][r];
        if (EPI == 0) {
          Cf[(size_t)m * N + col] = v;
        } else {
          const int bb2 = m >> 11, s = m & 2047;
          const int kt = s >> 5;
          const size_t tb = (size_t)(bb2 * 64 + kt);
          if (col < 4096) {
            Cq[(size_t)m * 4096 + col] = f2bf(v);
          } else if (col < 4224) {
            const int d = col - 4096, kr = s & 31;
            const int mk = kr >> 4, lii = kr & 15;
            const int kk = d >> 5, gg = (d >> 3) & 3, e = d & 7;
            Ck[(tb * 8 + mk * 4 + kk) * 512 + (gg * 16 + lii) * 8 + e] = f2bf(v);
          } else {
            const int d = col - 4224, kp = s & 31;
            const int mf = d >> 4, lii = d & 15;
            const int gg = kp >> 3, e = kp & 7;
            Cvt[(tb * 8 + mf) * 512 + (gg * 16 + lii) * 8 + e] = f2bf(v);
          }
        }
      }
    }
  }
}

// ---------------- flash attention (MQA) ----------------
// 1 wave/block; block p handles q-tiles {63-p, p} (uniform 66 tile-units).
// K double-buffered in registers; V issued at tile top; fragment-linear K/V loads.

__device__ __forceinline__ void load_ktile(s16x8 (&dst)[8], const u16* kf, size_t tb, int l) {
#pragma unroll
  for (int f = 0; f < 8; ++f)
    dst[f] = *(const s16x8*)&kf[(tb * 8 + f) * 512 + l * 8];
}

template<bool DIAG>
__device__ __forceinline__ void attn_tile(
    int kt, const u16* kf, const u16* vf, size_t bb64, int l, int li, int g,
    s16x8 (&use)[8], s16x8 (&fill)[8], bool do_fill,
    const s16x8 (&bq)[2][4], f32x4 (&acc)[8][2],
    float (&m_)[2], float (&lp)[2], float (&bias)[2],
    float c1, const float (&cjr)[8], float bstep, u16 (*Pw)[40]) {
  const size_t tb = bb64 + kt;
  s16x8 vr[8];
#pragma unroll
  for (int f = 0; f < 8; ++f)
    vr[f] = *(const s16x8*)&vf[(tb * 8 + f) * 512 + l * 8];
  if (do_fill) load_ktile(fill, kf, tb - 1, l);

  f32x4 sc[2][2];
  sc[0][0] = f4zero(); sc[0][1] = f4zero(); sc[1][0] = f4zero(); sc[1][1] = f4zero();
#pragma unroll
  for (int kk = 0; kk < 4; ++kk)
#pragma unroll
    for (int mk = 0; mk < 2; ++mk) {
      sc[mk][0] = MFMA_BF16(use[mk * 4 + kk], bq[0][kk], sc[mk][0]);
      sc[mk][1] = MFMA_BF16(use[mk * 4 + kk], bq[1][kk], sc[mk][1]);
    }

#pragma unroll
  for (int nq = 0; nq < 2; ++nq) {
    float sv[8];
    float pm = -3e38f;
    if (DIAG) {
#pragma unroll
      for (int mk = 0; mk < 2; ++mk)
#pragma unroll
        for (int r = 0; r < 4; ++r) {
          const int kd = mk * 16 + g * 4 + r - (nq * 16 + li);
          float s = fmaf(sc[mk][nq][r], c1, bias[nq] + cjr[mk * 4 + r]);
          s = (kd <= 0) ? s : -1e30f;
          sv[mk * 4 + r] = s;
          pm = fmaxf(pm, s);
        }
      pm = fmaxf(pm, __shfl_xor(pm, 16));
      pm = fmaxf(pm, __shfl_xor(pm, 32));
      m_[nq] = pm;
    } else {
#pragma unroll
      for (int mk = 0; mk < 2; ++mk)
#pragma unroll
        for (int r = 0; r < 4; ++r) {
          float s = fmaf(sc[mk][nq][r], c1, bias[nq] + cjr[mk * 4 + r]);
          sv[mk * 4 + r] = s;
          pm = fmaxf(pm, s);
        }
      if (__any(pm > m_[nq])) {
        pm = fmaxf(pm, __shfl_xor(pm, 16));
        pm = fmaxf(pm, __shfl_xor(pm, 32));
        const float nm = fmaxf(m_[nq], pm);
        const float scale = exp2f(m_[nq] - nm);
#pragma unroll
        for (int mf = 0; mf < 8; ++mf) acc[mf][nq] *= scale;
        lp[nq] *= scale;
        m_[nq] = nm;
      }
    }
    const float mref = m_[nq];
    float e[8];
#pragma unroll
    for (int j = 0; j < 8; ++j) e[j] = exp2f(sv[j] - mref);
    lp[nq] += ((e[0] + e[1]) + (e[2] + e[3])) + ((e[4] + e[5]) + (e[6] + e[7]));
#pragma unroll
    for (int mk = 0; mk < 2; ++mk) {
      uint2 wv;
      wv.x = pkbf(e[mk * 4 + 0], e[mk * 4 + 1]);
      wv.y = pkbf(e[mk * 4 + 2], e[mk * 4 + 3]);
      *reinterpret_cast<uint2*>(&Pw[nq * 16 + li][mk * 16 + g * 4]) = wv;
    }
    bias[nq] -= bstep;
  }

  s16x8 pb0 = *(const s16x8*)&Pw[li][g * 8];
  s16x8 pb1 = *(const s16x8*)&Pw[16 + li][g * 8];
#pragma unroll
  for (int mf = 0; mf < 8; ++mf) {
    acc[mf][0] = MFMA_BF16(vr[mf], pb0, acc[mf][0]);
    acc[mf][1] = MFMA_BF16(vr[mf], pb1, acc[mf][1]);
  }
}

__device__ __forceinline__ void attn_qtile(
    int qt, int h, int b, const u16* qbuf, const u16* kf, const u16* vf,
    u16* obuf, int l, int li, int g, float c1, float sl2, u16 (*Pw)[40]) {
  const int S = 2048;
  const int q0 = qt * 32;
  const size_t bb64 = (size_t)b * 64;

  s16x8 bq[2][4];
#pragma unroll
  for (int nq = 0; nq < 2; ++nq)
#pragma unroll
    for (int kk = 0; kk < 4; ++kk)
      bq[nq][kk] = *(const s16x8*)&qbuf[(size_t)(b * S + q0 + nq * 16 + li) * 4096
                                        + h * 128 + kk * 32 + g * 8];

  f32x4 acc[8][2];
#pragma unroll
  for (int mf = 0; mf < 8; ++mf) { acc[mf][0] = f4zero(); acc[mf][1] = f4zero(); }
  float m_[2] = {-3e38f, -3e38f};
  float lp[2] = {0.f, 0.f};

  float cjr[8];
#pragma unroll
  for (int j = 0; j < 8; ++j) cjr[j] = sl2 * (float)((j >> 2) * 16 + (j & 3));
  float bias[2];
#pragma unroll
  for (int nq = 0; nq < 2; ++nq)
    bias[nq] = sl2 * (float)(g * 4 - nq * 16 - li);
  const float bstep = sl2 * 32.f;

  s16x8 kA[8], kB[8];
  load_ktile(kA, kf, bb64 + qt, l);
  attn_tile<true>(qt, kf, vf, bb64, l, li, g, kA, kB, qt >= 1,
                  bq, acc, m_, lp, bias, c1, cjr, bstep, Pw);
  int kt = qt - 1;
  while (kt >= 1) {
    attn_tile<false>(kt, kf, vf, bb64, l, li, g, kB, kA, true,
                     bq, acc, m_, lp, bias, c1, cjr, bstep, Pw);
    attn_tile<false>(kt - 1, kf, vf, bb64, l, li, g, kA, kB, kt >= 2,
                     bq, acc, m_, lp, bias, c1, cjr, bstep, Pw);
    kt -= 2;
  }
  if (kt == 0)
    attn_tile<false>(0, kf, vf, bb64, l, li, g, kB, kA, false,
                     bq, acc, m_, lp, bias, c1, cjr, bstep, Pw);

#pragma unroll
  for (int nq = 0; nq < 2; ++nq) {
    float ls = lp[nq];
    ls += __shfl_xor(ls, 16);
    ls += __shfl_xor(ls, 32);
    const float inv = 1.f / ls;
    const size_t rowbase = (size_t)(b * S + q0 + nq * 16 + li) * 4096 + h * 128;
#pragma unroll
    for (int mf = 0; mf < 8; ++mf) {
      f32x4 v = acc[mf][nq];
      uint2 wv;
      wv.x = pkbf(v[0] * inv, v[1] * inv);
      wv.y = pkbf(v[2] * inv, v[3] * inv);
      *reinterpret_cast<uint2*>(&obuf[rowbase + mf * 16 + g * 4]) = wv;
    }
  }
}

__global__ __launch_bounds__(64, 2)
void attn_kernel(const u16* __restrict__ qbuf, const u16* __restrict__ kf,
                 const u16* __restrict__ vf, u16* __restrict__ obuf) {
  const int p = blockIdx.x, h = blockIdx.y, b = blockIdx.z;
  const int l = threadIdx.x, li = l & 15, g = l >> 4;
  const float L2E = 1.4426950408889634f;
  const float slope = exp2f(-0.25f * (float)(h + 1));
  const float c1 = 0.08838834764831845f * L2E;
  const float sl2 = slope * L2E;
  __shared__ __align__(16) u16 P[32][40];
  attn_qtile(63 - p, h, b, qbuf, kf, vf, obuf, l, li, g, c1, sl2, P);
  attn_qtile(p, h, b, qbuf, kf, vf, obuf, l, li, g, c1, sl2, P);
}

// ---------------- launch ----------------
extern "C" void kernel_launch(void* const* d_in, const int* in_sizes, int n_in,
                              void* d_out, int out_size, void* d_ws, size_t ws_size,
                              hipStream_t stream) {
  (void)in_sizes; (void)n_in; (void)out_size; (void)ws_size;
  const float* hidden = (const float*)d_in[0];
  const float* w_qkv = (const float*)d_in[1];
  const float* w_c = (const float*)d_in[2];
  float* out = (float*)d_out;
  char* ws = (char*)d_ws;

  // workspace layout (100 MB total)
  u16* hid_bf = (u16*)(ws + 0);            // 32 MB  (B*S,4096) bf16; reused as attn out
  u16* wT     = (u16*)(ws + 33554432);     // 34 MB  w_qkv^T then w_c^T (N,K) bf16
  u16* qbuf   = (u16*)(ws + 69206016);     // 32 MB  (B*S,4096) bf16
  u16* kbuf   = (u16*)(ws + 102760448);    // 1 MB   K fragment-linear
  u16* vtbuf  = (u16*)(ws + 103809024);    // 1 MB   V fragment-linear

  cvt_bf16_kernel<<<16384, 256, 0, stream>>>((const float4*)hidden, hid_bf, 4194304);
  transpose_cvt_kernel<<<dim3(136, 128), dim3(32, 8), 0, stream>>>(w_qkv, wT, 4096, 4352);
  gemm128_kernel<1><<<dim3(17, 32), 512, 0, stream>>>(hid_bf, wT, nullptr, qbuf, kbuf, vtbuf,
                                                      4352, 4096);
  attn_kernel<<<dim3(32, 32, 2), 64, 0, stream>>>(qbuf, kbuf, vtbuf, hid_bf);
  transpose_cvt_kernel<<<dim3(128, 128), dim3(32, 8), 0, stream>>>(w_c, wT, 4096, 4096);
  gemm128_kernel<0><<<dim3(16, 32), 512, 0, stream>>>(hid_bf, wT, out, nullptr, nullptr, nullptr,
                                                      4096, 4096);
}

// Round 17
// 479.935 us; speedup vs baseline: 1.3434x; 1.0024x over previous
//
#include <hip/hip_runtime.h>
#include <hip/hip_bf16.h>

typedef unsigned short u16;
typedef unsigned int u32;
typedef __attribute__((ext_vector_type(8))) short s16x8;
typedef __attribute__((ext_vector_type(4))) float f32x4;

#define MFMA_BF16(a, b, c) __builtin_amdgcn_mfma_f32_16x16x32_bf16(a, b, c, 0, 0, 0)

__device__ __forceinline__ u16 f2bf(float f) {
  union { float f; u32 u; } c; c.f = f;
  return (u16)((c.u + 0x7FFFu + ((c.u >> 16) & 1u)) >> 16);
}

__device__ __forceinline__ u32 pkbf(float a, float b) {
  float2 t; t.x = a; t.y = b;
  __hip_bfloat162 h = __float22bfloat162_rn(t);
  union { __hip_bfloat162 h; u32 u; } c; c.h = h; return c.u;
}

__device__ __forceinline__ void gll16(const void* g, void* l) {
  __builtin_amdgcn_global_load_lds((const __attribute__((address_space(1))) void*)g,
                                   (__attribute__((address_space(3))) void*)l, 16, 0, 0);
}

__device__ __forceinline__ f32x4 f4zero() { f32x4 z = {0.f, 0.f, 0.f, 0.f}; return z; }

// ---------------- prep: f32 -> bf16 convert ----------------
__global__ void cvt_bf16_kernel(const float4* __restrict__ in, u16* __restrict__ out, int n4) {
  int i = blockIdx.x * 256 + threadIdx.x;
  if (i >= n4) return;
  float4 v = in[i];
  uint2 w;
  w.x = (u32)f2bf(v.x) | ((u32)f2bf(v.y) << 16);
  w.y = (u32)f2bf(v.z) | ((u32)f2bf(v.w) << 16);
  *reinterpret_cast<uint2*>(out + (size_t)i * 4) = w;
}

// ---------------- prep: transpose + convert (R x C f32 -> C x R bf16) ----------------
__global__ void transpose_cvt_kernel(const float* __restrict__ in, u16* __restrict__ out,
                                     int R, int C) {
  __shared__ float tile[32][33];
  int tx = threadIdx.x, ty = threadIdx.y;
  int r0 = blockIdx.y * 32, c0 = blockIdx.x * 32;
#pragma unroll
  for (int i = 0; i < 32; i += 8)
    tile[ty + i][tx] = in[(size_t)(r0 + ty + i) * C + c0 + tx];
  __syncthreads();
#pragma unroll
  for (int i = 0; i < 32; i += 8)
    out[(size_t)(c0 + ty + i) * R + r0 + tx] = f2bf(tile[tx][ty + i]);
}

// =====================================================================================
// 128x256 GEMM, BK=32, 4-WAVE blocks (256 thr), wave tile 64x128 (2M x 2N wave grid).
// Same drift schedule / triple-buffered LDS / paired-row XOR layout / locality walk
// as the proven R14 kernel; only the occupancy<->register trade changes:
//   2 waves/SIMD (256-reg budget) fits acc[4][8]=128 + operands 48 + addr ~20.
//   Operand LDS read drops 512 -> 384 B per MFMA; per-CU-period LDS 144 KB (1125 cyc)
//   < MFMA 1242 cyc -> MFMA becomes the binding resource (was LDS at 64x64 tiles).
// LDS: A 3x8 KB + B 3x16 KB = 72 KB -> 2 blocks/CU (144 KB) for cross-block TLP.
// Stage unit = 6 gll16/thread (2 A halves + 4 B quarters; linear tt*16 dest, source
// row = 2*(tt>>3)+(sg>>2) (+64j), granule sg&3, sg=(tt&7)^((tt>>3)&7)).
// vmcnt ledger: steady tile end outstanding = stage(t+1)+stage(t+2) = 12 -> VM6
// drains stage(t+1) exactly. Prologue VM6 (drains stage0). Tile126 VM0; tile127 none.
// L2-locality walk: bn = raw>>5, bm = ((raw>>3)&3)*8 + (raw&7) (bijective, R14-proven).
// NOTE (R9/R15 lesson): reg ledger must be <= budget with margin; here 196 <= 256.
// EPI 1: q/k/v scatter epilogue (KV cols 4096..4351 are the bn=16 block).
// =====================================================================================

#define BARRIER __builtin_amdgcn_s_barrier()
#define SCHEDB __builtin_amdgcn_sched_barrier(0)
#define PRIO1 __builtin_amdgcn_s_setprio(1)
#define PRIO0 __builtin_amdgcn_s_setprio(0)
#define VM6 asm volatile("s_waitcnt vmcnt(6)" ::: "memory")
#define VM0 asm volatile("s_waitcnt vmcnt(0)" ::: "memory")
#define NOPW do {} while (0)

#define PAB(P) ((P) * 8192)
#define PBB(P) (24576 + (P) * 16384)

#define RDAB(P) do { _Pragma("unroll")                                                   \
  for (int mi2 = 0; mi2 < 4; ++mi2)                                                      \
    a[mi2] = *(const s16x8*)(smem + PAB(P) + aOff + mi2*1024);                           \
  _Pragma("unroll")                                                                      \
  for (int ni2 = 0; ni2 < 8; ++ni2)                                                      \
    b[ni2] = *(const s16x8*)(smem + PBB(P) + bOff + ni2*1024);                           \
} while (0)

#define MFMA32 do { _Pragma("unroll")                                                    \
  for (int mi2 = 0; mi2 < 4; ++mi2) { _Pragma("unroll")                                  \
    for (int ni2 = 0; ni2 < 8; ++ni2)                                                    \
      acc[mi2][ni2] = MFMA_BF16(a[mi2], b[ni2], acc[mi2][ni2]);                          \
  } } while (0)

#define STAGE6(P, kn) do {                                                               \
  gll16(srcA + (kn), smem + PAB(P) + tt*16);                                             \
  gll16(srcA + (size_t)64 * K + (kn), smem + PAB(P) + 4096 + tt*16);                     \
  _Pragma("unroll")                                                                      \
  for (int j = 0; j < 4; ++j)                                                            \
    gll16(srcB0 + (size_t)(j * 64) * K + (kn), smem + PBB(P) + j*4096 + tt*16);          \
} while (0)

#define TILE_S(PR, PS, T) do {                                                           \
  s16x8 a[4], b[8];                                                                      \
  RDAB(PR);                                                                              \
  STAGE6(PS, ((T) + 2) * 32);                                                            \
  SCHEDB;                                                                                \
  PRIO1; MFMA32; PRIO0;                                                                  \
  SCHEDB;                                                                                \
  VM6;                                                                                   \
  BARRIER;                                                                               \
} while (0)

#define TILE_T(PR, WAIT) do {                                                            \
  s16x8 a[4], b[8];                                                                      \
  RDAB(PR);                                                                              \
  SCHEDB;                                                                                \
  PRIO1; MFMA32; PRIO0;                                                                  \
  SCHEDB;                                                                                \
  WAIT;                                                                                  \
  BARRIER;                                                                               \
} while (0)

template<int EPI>
__global__ __launch_bounds__(256, 2)
void gemm128_kernel(const u16* __restrict__ A, const u16* __restrict__ Bt,
                    float* __restrict__ Cf, u16* __restrict__ Cq,
                    u16* __restrict__ Ck, u16* __restrict__ Cvt,
                    int N, int K) {
  __shared__ __align__(16) char smem[73728];
  const int tt = threadIdx.x;
  const int w = tt >> 6, l = tt & 63;
  const int li = l & 15, g = l >> 4;
  const int wm = w >> 1, wn = w & 1;

  // L2-locality walk (bijective): 32 consecutive raw ids share one bn (B panel);
  // per-XCD (raw&7 fixed) bm set is {x, x+8, x+16, x+24} for A locality.
  const int gx = gridDim.x;
  const int raw = blockIdx.y * gx + blockIdx.x;
  const int bn = raw >> 5;
  const int bm = ((raw >> 3) & 3) * 8 + (raw & 7);

  f32x4 acc[4][8];
#pragma unroll
  for (int i = 0; i < 4; ++i)
#pragma unroll
    for (int j = 0; j < 8; ++j) acc[i][j] = f4zero();

  // ---- staging sources (inverse paired-row + slot-XOR map on the source) ----
  const int sg = (tt & 7) ^ ((tt >> 3) & 7);
  const int ar = 2 * (tt >> 3) + (sg >> 2);   // in [0,64)
  const int aq = sg & 3;
  const u16* srcA = A + (size_t)(bm * 128 + ar) * K + aq * 8;
  const u16* srcB0 = Bt + (size_t)(bn * 256 + ar) * K + aq * 8;

  // ---- ds_read per-thread byte offsets (slot XOR by (li>>1)&7, 128B lines) ----
  const int slot = (((li & 1) * 4 + g) ^ ((li >> 1) & 7)) * 16;
  const int aOff = wm * 4096 + (li >> 1) * 128 + slot;   // + mi*1024 per fragment
  const int bOff = wn * 8192 + (li >> 1) * 128 + slot;   // + ni*1024 per fragment

  // ---- prologue: stage tiles 0,1 into parities 0,1; drain stage0 only ----
  STAGE6(0, 0);
  STAGE6(1, 32);
  VM6;
  BARRIER;

  // ---- main loop: 128 K-tiles (K == 4096, BK == 32), 3 per iteration ----
  for (int t3 = 0; t3 < 126; t3 += 3) {
    TILE_S(0, 2, t3);
    TILE_S(1, 0, t3 + 1);
    TILE_S(2, 1, t3 + 2);
  }
  TILE_T(0, VM0);    // tile 126: drain stage(127)
  TILE_T(1, NOPW);   // tile 127

  // ---- epilogue ----
#pragma unroll
  for (int mi = 0; mi < 4; ++mi) {
#pragma unroll
    for (int ni = 0; ni < 8; ++ni) {
      const int row0 = bm * 128 + wm * 64 + mi * 16 + g * 4;
      const int col = bn * 256 + wn * 128 + ni * 16 + li;
#pragma unroll
      for (int r = 0; r < 4; ++r) {
        const int m = row0 + r;
        const float v = acc[mi][ni][r];
        if (EPI == 0) {
          Cf[(size_t)m * N + col] = v;
        } else {
          const int bb2 = m >> 11, s = m & 2047;
          const int kt = s >> 5;
          const size_t tb = (size_t)(bb2 * 64 + kt);
          if (col < 4096) {
            Cq[(size_t)m * 4096 + col] = f2bf(v);
          } else if (col < 4224) {
            const int d = col - 4096, kr = s & 31;
            const int mk = kr >> 4, lii = kr & 15;
            const int kk = d >> 5, gg = (d >> 3) & 3, e = d & 7;
            Ck[(tb * 8 + mk * 4 + kk) * 512 + (gg * 16 + lii) * 8 + e] = f2bf(v);
          } else {
            const int d = col - 4224, kp = s & 31;
            const int mf = d >> 4, lii = d & 15;
            const int gg = kp >> 3, e = kp & 7;
            Cvt[(tb * 8 + mf) * 512 + (gg * 16 + lii) * 8 + e] = f2bf(v);
          }
        }
      }
    }
  }
}

// ---------------- flash attention (MQA) ----------------
// 1 wave/block; block p handles q-tiles {63-p, p} (uniform 66 tile-units).
// K double-buffered in registers; V issued at tile top; fragment-linear K/V loads.

__device__ __forceinline__ void load_ktile(s16x8 (&dst)[8], const u16* kf, size_t tb, int l) {
#pragma unroll
  for (int f = 0; f < 8; ++f)
    dst[f] = *(const s16x8*)&kf[(tb * 8 + f) * 512 + l * 8];
}

template<bool DIAG>
__device__ __forceinline__ void attn_tile(
    int kt, const u16* kf, const u16* vf, size_t bb64, int l, int li, int g,
    s16x8 (&use)[8], s16x8 (&fill)[8], bool do_fill,
    const s16x8 (&bq)[2][4], f32x4 (&acc)[8][2],
    float (&m_)[2], float (&lp)[2], float (&bias)[2],
    float c1, const float (&cjr)[8], float bstep, u16 (*Pw)[40]) {
  const size_t tb = bb64 + kt;
  s16x8 vr[8];
#pragma unroll
  for (int f = 0; f < 8; ++f)
    vr[f] = *(const s16x8*)&vf[(tb * 8 + f) * 512 + l * 8];
  if (do_fill) load_ktile(fill, kf, tb - 1, l);

  f32x4 sc[2][2];
  sc[0][0] = f4zero(); sc[0][1] = f4zero(); sc[1][0] = f4zero(); sc[1][1] = f4zero();
#pragma unroll
  for (int kk = 0; kk < 4; ++kk)
#pragma unroll
    for (int mk = 0; mk < 2; ++mk) {
      sc[mk][0] = MFMA_BF16(use[mk * 4 + kk], bq[0][kk], sc[mk][0]);
      sc[mk][1] = MFMA_BF16(use[mk * 4 + kk], bq[1][kk], sc[mk][1]);
    }

#pragma unroll
  for (int nq = 0; nq < 2; ++nq) {
    float sv[8];
    float pm = -3e38f;
    if (DIAG) {
#pragma unroll
      for (int mk = 0; mk < 2; ++mk)
#pragma unroll
        for (int r = 0; r < 4; ++r) {
          const int kd = mk * 16 + g * 4 + r - (nq * 16 + li);
          float s = fmaf(sc[mk][nq][r], c1, bias[nq] + cjr[mk * 4 + r]);
          s = (kd <= 0) ? s : -1e30f;
          sv[mk * 4 + r] = s;
          pm = fmaxf(pm, s);
        }
      pm = fmaxf(pm, __shfl_xor(pm, 16));
      pm = fmaxf(pm, __shfl_xor(pm, 32));
      m_[nq] = pm;
    } else {
#pragma unroll
      for (int mk = 0; mk < 2; ++mk)
#pragma unroll
        for (int r = 0; r < 4; ++r) {
          float s = fmaf(sc[mk][nq][r], c1, bias[nq] + cjr[mk * 4 + r]);
          sv[mk * 4 + r] = s;
          pm = fmaxf(pm, s);
        }
      if (__any(pm > m_[nq])) {
        pm = fmaxf(pm, __shfl_xor(pm, 16));
        pm = fmaxf(pm, __shfl_xor(pm, 32));
        const float nm = fmaxf(m_[nq], pm);
        const float scale = exp2f(m_[nq] - nm);
#pragma unroll
        for (int mf = 0; mf < 8; ++mf) acc[mf][nq] *= scale;
        lp[nq] *= scale;
        m_[nq] = nm;
      }
    }
    const float mref = m_[nq];
    float e[8];
#pragma unroll
    for (int j = 0; j < 8; ++j) e[j] = exp2f(sv[j] - mref);
    lp[nq] += ((e[0] + e[1]) + (e[2] + e[3])) + ((e[4] + e[5]) + (e[6] + e[7]));
#pragma unroll
    for (int mk = 0; mk < 2; ++mk) {
      uint2 wv;
      wv.x = pkbf(e[mk * 4 + 0], e[mk * 4 + 1]);
      wv.y = pkbf(e[mk * 4 + 2], e[mk * 4 + 3]);
      *reinterpret_cast<uint2*>(&Pw[nq * 16 + li][mk * 16 + g * 4]) = wv;
    }
    bias[nq] -= bstep;
  }

  s16x8 pb0 = *(const s16x8*)&Pw[li][g * 8];
  s16x8 pb1 = *(const s16x8*)&Pw[16 + li][g * 8];
#pragma unroll
  for (int mf = 0; mf < 8; ++mf) {
    acc[mf][0] = MFMA_BF16(vr[mf], pb0, acc[mf][0]);
    acc[mf][1] = MFMA_BF16(vr[mf], pb1, acc[mf][1]);
  }
}

__device__ __forceinline__ void attn_qtile(
    int qt, int h, int b, const u16* qbuf, const u16* kf, const u16* vf,
    u16* obuf, int l, int li, int g, float c1, float sl2, u16 (*Pw)[40]) {
  const int S = 2048;
  const int q0 = qt * 32;
  const size_t bb64 = (size_t)b * 64;

  s16x8 bq[2][4];
#pragma unroll
  for (int nq = 0; nq < 2; ++nq)
#pragma unroll
    for (int kk = 0; kk < 4; ++kk)
      bq[nq][kk] = *(const s16x8*)&qbuf[(size_t)(b * S + q0 + nq * 16 + li) * 4096
                                        + h * 128 + kk * 32 + g * 8];

  f32x4 acc[8][2];
#pragma unroll
  for (int mf = 0; mf < 8; ++mf) { acc[mf][0] = f4zero(); acc[mf][1] = f4zero(); }
  float m_[2] = {-3e38f, -3e38f};
  float lp[2] = {0.f, 0.f};

  float cjr[8];
#pragma unroll
  for (int j = 0; j < 8; ++j) cjr[j] = sl2 * (float)((j >> 2) * 16 + (j & 3));
  float bias[2];
#pragma unroll
  for (int nq = 0; nq < 2; ++nq)
    bias[nq] = sl2 * (float)(g * 4 - nq * 16 - li);
  const float bstep = sl2 * 32.f;

  s16x8 kA[8], kB[8];
  load_ktile(kA, kf, bb64 + qt, l);
  attn_tile<true>(qt, kf, vf, bb64, l, li, g, kA, kB, qt >= 1,
                  bq, acc, m_, lp, bias, c1, cjr, bstep, Pw);
  int kt = qt - 1;
  while (kt >= 1) {
    attn_tile<false>(kt, kf, vf, bb64, l, li, g, kB, kA, true,
                     bq, acc, m_, lp, bias, c1, cjr, bstep, Pw);
    attn_tile<false>(kt - 1, kf, vf, bb64, l, li, g, kA, kB, kt >= 2,
                     bq, acc, m_, lp, bias, c1, cjr, bstep, Pw);
    kt -= 2;
  }
  if (kt == 0)
    attn_tile<false>(0, kf, vf, bb64, l, li, g, kB, kA, false,
                     bq, acc, m_, lp, bias, c1, cjr, bstep, Pw);

#pragma unroll
  for (int nq = 0; nq < 2; ++nq) {
    float ls = lp[nq];
    ls += __shfl_xor(ls, 16);
    ls += __shfl_xor(ls, 32);
    const float inv = 1.f / ls;
    const size_t rowbase = (size_t)(b * S + q0 + nq * 16 + li) * 4096 + h * 128;
#pragma unroll
    for (int mf = 0; mf < 8; ++mf) {
      f32x4 v = acc[mf][nq];
      uint2 wv;
      wv.x = pkbf(v[0] * inv, v[1] * inv);
      wv.y = pkbf(v[2] * inv, v[3] * inv);
      *reinterpret_cast<uint2*>(&obuf[rowbase + mf * 16 + g * 4]) = wv;
    }
  }
}

__global__ __launch_bounds__(64, 2)
void attn_kernel(const u16* __restrict__ qbuf, const u16* __restrict__ kf,
                 const u16* __restrict__ vf, u16* __restrict__ obuf) {
  const int p = blockIdx.x, h = blockIdx.y, b = blockIdx.z;
  const int l = threadIdx.x, li = l & 15, g = l >> 4;
  const float L2E = 1.4426950408889634f;
  const float slope = exp2f(-0.25f * (float)(h + 1));
  const float c1 = 0.08838834764831845f * L2E;
  const float sl2 = slope * L2E;
  __shared__ __align__(16) u16 P[32][40];
  attn_qtile(63 - p, h, b, qbuf, kf, vf, obuf, l, li, g, c1, sl2, P);
  attn_qtile(p, h, b, qbuf, kf, vf, obuf, l, li, g, c1, sl2, P);
}

// ---------------- launch ----------------
extern "C" void kernel_launch(void* const* d_in, const int* in_sizes, int n_in,
                              void* d_out, int out_size, void* d_ws, size_t ws_size,
                              hipStream_t stream) {
  (void)in_sizes; (void)n_in; (void)out_size; (void)ws_size;
  const float* hidden = (const float*)d_in[0];
  const float* w_qkv = (const float*)d_in[1];
  const float* w_c = (const float*)d_in[2];
  float* out = (float*)d_out;
  char* ws = (char*)d_ws;

  // workspace layout (100 MB total)
  u16* hid_bf = (u16*)(ws + 0);            // 32 MB  (B*S,4096) bf16; reused as attn out
  u16* wT     = (u16*)(ws + 33554432);     // 34 MB  w_qkv^T then w_c^T (N,K) bf16
  u16* qbuf   = (u16*)(ws + 69206016);     // 32 MB  (B*S,4096) bf16
  u16* kbuf   = (u16*)(ws + 102760448);    // 1 MB   K fragment-linear
  u16* vtbuf  = (u16*)(ws + 103809024);    // 1 MB   V fragment-linear

  cvt_bf16_kernel<<<16384, 256, 0, stream>>>((const float4*)hidden, hid_bf, 4194304);
  transpose_cvt_kernel<<<dim3(136, 128), dim3(32, 8), 0, stream>>>(w_qkv, wT, 4096, 4352);
  gemm128_kernel<1><<<dim3(17, 32), 256, 0, stream>>>(hid_bf, wT, nullptr, qbuf, kbuf, vtbuf,
                                                      4352, 4096);
  attn_kernel<<<dim3(32, 32, 2), 64, 0, stream>>>(qbuf, kbuf, vtbuf, hid_bf);
  transpose_cvt_kernel<<<dim3(128, 128), dim3(32, 8), 0, stream>>>(w_c, wT, 4096, 4096);
  gemm128_kernel<0><<<dim3(16, 32), 256, 0, stream>>>(hid_bf, wT, out, nullptr, nullptr, nullptr,
                                                      4096, 4096);
}